// Round 1
// baseline (34.749 us; speedup 1.0000x reference)
//
#include <hip/hip_runtime.h>

// Problem geometry (fixed by the reference):
//   embeddings: (8, 2048, 768) fp32
//   W: (1536,) fp32  -> W_left = W[:768], W_right = W[768:]
//   b: (1,) fp32
//   out[b,i,j] = dot(emb[b,i,:], W_left) + dot(emb[b,j,:], W_right) + b[0]
#define PB_H 768
#define PB_L 2048
#define PB_B 8
#define PB_ROWS (PB_B * PB_L)   // 16384

// Kernel 1: per-row dual dot product.
// One wave (64 lanes) per row; 4 waves per 256-thread block.
// Lane k reads float4s at element offsets {0,256,512}*+4k -> each of the 3
// loads is a contiguous 1 KiB wave transaction.
__global__ void probe_dot_kernel(const float* __restrict__ emb,
                                 const float* __restrict__ W,
                                 const float* __restrict__ bptr,
                                 float* __restrict__ left,
                                 float* __restrict__ right) {
    const int wave = threadIdx.x >> 6;
    const int lane = threadIdx.x & 63;
    const int row  = (blockIdx.x << 2) + wave;          // [0, 16384)

    const float4* e  = reinterpret_cast<const float4*>(emb + (size_t)row * PB_H);
    const float4* wl = reinterpret_cast<const float4*>(W);
    const float4* wr = reinterpret_cast<const float4*>(W + PB_H);

    float accl = 0.f, accr = 0.f;
#pragma unroll
    for (int k = 0; k < 3; ++k) {
        const int idx = k * 64 + lane;                  // float4 index within row
        float4 ev = e[idx];
        float4 lv = wl[idx];
        float4 rv = wr[idx];
        accl += ev.x * lv.x + ev.y * lv.y + ev.z * lv.z + ev.w * lv.w;
        accr += ev.x * rv.x + ev.y * rv.y + ev.z * rv.z + ev.w * rv.w;
    }

    // 64-lane butterfly reduction
#pragma unroll
    for (int off = 32; off >= 1; off >>= 1) {
        accl += __shfl_xor(accl, off);
        accr += __shfl_xor(accr, off);
    }

    if (lane == 0) {
        left[row]  = accl + bptr[0];   // fold bias into left
        right[row] = accr;
    }
}

// Kernel 2: broadcast add. One float4 of output per thread.
// out is (8, 2048, 2048); float4 index t: j4 = t & 511, row = t >> 9,
// b = row >> 11. right row (8 KiB per batch) is L1/L2 resident.
__global__ void probe_bcast_kernel(const float* __restrict__ left,
                                   const float* __restrict__ right,
                                   float4* __restrict__ out) {
    const long long t = (long long)blockIdx.x * blockDim.x + threadIdx.x;
    const int j4  = (int)(t & 511);         // 2048/4 = 512 float4 per row
    const int row = (int)(t >> 9);          // b*2048 + i
    const int b   = row >> 11;

    const float lv = left[row];
    const float4 rv =
        reinterpret_cast<const float4*>(right + ((size_t)b << 11))[j4];

    float4 o;
    o.x = lv + rv.x;
    o.y = lv + rv.y;
    o.z = lv + rv.z;
    o.w = lv + rv.w;
    out[t] = o;
}

extern "C" void kernel_launch(void* const* d_in, const int* in_sizes, int n_in,
                              void* d_out, int out_size, void* d_ws, size_t ws_size,
                              hipStream_t stream) {
    const float* emb  = (const float*)d_in[0];
    const float* W    = (const float*)d_in[1];
    const float* bias = (const float*)d_in[2];
    float* out = (float*)d_out;

    float* left  = (float*)d_ws;            // 16384 floats
    float* right = left + PB_ROWS;          // 16384 floats (128 KiB total)

    // Kernel 1: 16384 rows / 4 waves per block = 4096 blocks
    probe_dot_kernel<<<4096, 256, 0, stream>>>(emb, W, bias, left, right);

    // Kernel 2: 8*2048*2048 / 4 = 8,388,608 float4s / 256 = 32768 blocks
    probe_bcast_kernel<<<32768, 256, 0, stream>>>(left, right, (float4*)out);
}